// Round 22
// baseline (45.644 us; speedup 1.0000x reference)
//
#include <hip/hip_runtime.h>

#define HW 262144            // 512*512
#define TSIZE 524288         // 2^19 entries per level
#define HMASK 524287u
#define PRIME2 2654435761u

#define NLDS 12              // levels 0..11 staged in LDS (paired f16 cells)
#define ETOT 13038           // sum of (NS[l]+2)^2 for l<12 (cells)
#define EPAD 13040           // padded so EPAD*8 is uint4 multiple (104,320 B)
#define QTOT 42030           // 75^2+90^2+108^2+129^2 cells (levels 12..15)
#define QU4_OFF 6520         // EPAD u64 = 104,320 B -> /16 = 6520 uint4
#define WS_NEED (104320 + QTOT * 16)   // 776,800 B
#define BLK 1024             // 256 blocks = 1/CU exactly, 16 waves/CU, no tail
#define PPT 4                // pixels per thread
#define SCALE 1024.0f        // lift f16 values out of subnormal range (exact pow2)
#define INV_SCALE 0.0009765625f  // 2^-10, exact

typedef float    f4v __attribute__((ext_vector_type(4)));
typedef _Float16 h2v __attribute__((ext_vector_type(2)));
typedef _Float16 h8v __attribute__((ext_vector_type(8)));

__device__ __constant__ int c_W12[12]   = {10, 11, 13, 15, 18, 22, 26, 31, 37, 44, 52, 63};
__device__ __constant__ int c_EOFF[13]  = {0, 100, 221, 390, 615, 939, 1423, 2099,
                                           3060, 4429, 6365, 9069, 13038};
__device__ __constant__ int c_WQ[4]     = {75, 90, 108, 129};
__device__ __constant__ int c_QOFF[5]   = {0, 5625, 13725, 25389, 42030};

// Reference semantics (locked R1-R7): JAX/XLA f32:
//   hx = int32(fl32(cx*n)); bx = floorf(fl32(cx*rcp)), rcp = fl32(1/fl32(1/n));
//   NS[15] = 127.
// Ladder: R7 93 -> R11 47.9 -> R19 42.8 -> R21 41.0 (12 LDS + 4 quad, no tail).
// Budget at R21: stores ~20us floor; LDS 192 b32 reads/thread + 3.4M conflict
// cycles is the biggest non-floor term. R22: paired-u64 LDS cells
// {e(i,j), e(i+1,j)} -> 4 corner reads = 2 aligned ds_read_b64 (96 insts),
// 104.3KB LDS, 1024-thr blocks, 256 blocks = 1/CU, still 16 waves/CU.

__device__ __forceinline__ unsigned pack_h2(float a, float b) {
    h2v h; h[0] = (_Float16)(a * SCALE); h[1] = (_Float16)(b * SCALE);
    return __builtin_bit_cast(unsigned, h);
}

// ---- phase 1: build dense scratch: u64 pair cells (lvls 0-11) + f16 quads (12-15) ----
__global__ __launch_bounds__(256)
void dehash_kernel(const float* __restrict__ table, unsigned* __restrict__ wsu)
{
    const int e = blockIdx.x * 256 + threadIdx.x;
    const float2* __restrict__ tab2 = reinterpret_cast<const float2*>(table);

    if (e < ETOT) {
        int l = 0;
        #pragma unroll
        for (int i = 1; i < NLDS; ++i) l += (e >= c_EOFF[i]);
        const int W   = c_W12[l];
        const int rel = e - c_EOFF[l];
        const int j   = rel / W;
        const int i2  = rel - j * W;
        const float2* __restrict__ tabl = tab2 + (size_t)l * TSIZE;
        const unsigned jp = (unsigned)j * PRIME2;
        const float2 a = tabl[((unsigned)i2       ^ jp) & HMASK];
        const float2 b = tabl[((unsigned)(i2 + 1) ^ jp) & HMASK];  // i2=W-1 never read
        uint2 pr;
        pr.x = pack_h2(a.x, a.y);
        pr.y = pack_h2(b.x, b.y);
        reinterpret_cast<uint2*>(wsu)[e] = pr;
    } else if (e < ETOT + QTOT) {
        const int eq = e - ETOT;
        int k = 0;
        #pragma unroll
        for (int i = 1; i < 4; ++i) k += (eq >= c_QOFF[i]);
        const int W   = c_WQ[k];
        const int rel = eq - c_QOFF[k];
        const int j   = rel / W;
        const int i2  = rel - j * W;
        const float2* __restrict__ tabl = tab2 + (size_t)(12 + k) * TSIZE;
        const unsigned jp0 = (unsigned)j * PRIME2;
        const unsigned jp1 = (unsigned)(j + 1) * PRIME2;
        const float2 f00 = tabl[((unsigned)i2       ^ jp0) & HMASK];
        const float2 f10 = tabl[((unsigned)(i2 + 1) ^ jp0) & HMASK];
        const float2 f01 = tabl[((unsigned)i2       ^ jp1) & HMASK];
        const float2 f11 = tabl[((unsigned)(i2 + 1) ^ jp1) & HMASK];
        uint4 q;
        q.x = pack_h2(f00.x, f00.y);
        q.y = pack_h2(f10.x, f10.y);
        q.z = pack_h2(f01.x, f01.y);
        q.w = pack_h2(f11.x, f11.y);
        reinterpret_cast<uint4*>(wsu)[QU4_OFF + eq] = q;
    }
}

__device__ __forceinline__ float2 dec_h2(unsigned u) {
    const h2v h = __builtin_bit_cast(h2v, u);
    return make_float2((float)h[0], (float)h[1]);
}

// ---- phase 2: fused encode: 12 pair-LDS levels + 4 quad-gather levels ----
__global__ __launch_bounds__(BLK)
void hashenc_fused(const float* __restrict__ coord,
                   const unsigned* __restrict__ wsu,
                   float* __restrict__ out)
{
    constexpr int NS[12]   = {8, 9, 11, 13, 16, 20, 24, 29, 35, 42, 50, 61};
    constexpr int W12[12]  = {10, 11, 13, 15, 18, 22, 26, 31, 37, 44, 52, 63};
    constexpr int EOFF[12] = {0, 100, 221, 390, 615, 939, 1423, 2099, 3060, 4429,
                              6365, 9069};
    constexpr int NSD[4]   = {73, 88, 106, 127};
    constexpr int WQ[4]    = {75, 90, 108, 129};
    constexpr int QOFF[4]  = {0, 5625, 13725, 25389};

    __shared__ __align__(16) uint2 smem[EPAD];   // 104,320 B -> 1 block/CU @1024thr

    // ---- stage pair cells from dense scratch (coalesced uint4) ----
    {
        const uint4* __restrict__ src = reinterpret_cast<const uint4*>(wsu);
        uint4* __restrict__ dst = reinterpret_cast<uint4*>(smem);
        for (int e = threadIdx.x; e < EPAD / 2; e += BLK)
            dst[e] = src[e];
    }

    const int g   = blockIdx.x * BLK + threadIdx.x;   // 0..262143
    const int P   = g << 2;                           // first of 4 pixels
    const int b   = P >> 18;                          // batch (HW = 2^18)
    const int pos = P & (HW - 1);

    const float* cbase = coord + (size_t)b * (2 * HW);
    const float4 cx4 = *reinterpret_cast<const float4*>(cbase + pos);
    const float4 cy4 = *reinterpret_cast<const float4*>(cbase + HW + pos);
    const float cxa[PPT] = {cx4.x, cx4.y, cx4.z, cx4.w};
    const float cya[PPT] = {cy4.x, cy4.y, cy4.z, cy4.w};

    float* outb = out + (size_t)b * (32 * HW) + pos;

    __syncthreads();

    // ---- issue all 16 direct quad loads NOW (latency hides under LDS work) ----
    uint4 q[4][PPT];
    {
        const uint4* __restrict__ quad = reinterpret_cast<const uint4*>(wsu) + QU4_OFF;
        #pragma unroll
        for (int k = 0; k < 4; ++k) {
            const float n = (float)NSD[k];
            #pragma unroll
            for (int p = 0; p < PPT; ++p) {
                const int hx = (int)(cxa[p] * n);
                const int hy = (int)(cya[p] * n);
                q[k][p] = quad[QOFF[k] + hy * WQ[k] + hx];
            }
        }
    }

    // ---- pair-LDS levels 0..11: 2 aligned ds_read_b64 per pixel-level ----
    #pragma unroll
    for (int l = 0; l < NLDS; ++l) {
        const float n   = (float)NS[l];
        const float inv = 1.0f / n;
        const float rcp = 1.0f / inv;
        const int   W   = W12[l];
        const uint2* __restrict__ sl = smem + EOFF[l];

        float o0[PPT], o1[PPT];
        #pragma unroll
        for (int p = 0; p < PPT; ++p) {
            const float cx = cxa[p], cy = cya[p];
            const int hx = (int)(cx * n);
            const int hy = (int)(cy * n);
            const float bx = floorf(cx * rcp);
            const float by = floorf(cy * rcp);

            const int base = hy * W + hx;
            const uint2 p0 = sl[base];        // f00 | f10
            const uint2 p1 = sl[base + W];    // f01 | f11
            const float2 f00 = dec_h2(p0.x);
            const float2 f10 = dec_h2(p0.y);
            const float2 f01 = dec_h2(p1.x);
            const float2 f11 = dec_h2(p1.y);

            const float wx_lo = ((bx + 1.0f) * inv - cx) * n;
            const float wx_hi = (cx - bx * inv) * n;
            const float wy_lo = ((by + 1.0f) * inv - cy) * n;
            const float wy_hi = (cy - by * inv) * n;

            const float r1x = f00.x * wx_lo + f10.x * wx_hi;
            const float r1y = f00.y * wx_lo + f10.y * wx_hi;
            const float r2x = f01.x * wx_lo + f11.x * wx_hi;
            const float r2y = f01.y * wx_lo + f11.y * wx_hi;
            o0[p] = (r1x * wy_lo + r2x * wy_hi) * INV_SCALE;
            o1[p] = (r1y * wy_lo + r2y * wy_hi) * INV_SCALE;
        }
        __builtin_nontemporal_store(f4v{o0[0], o0[1], o0[2], o0[3]},
                                    (f4v*)(outb + (size_t)(2 * l)     * HW));
        __builtin_nontemporal_store(f4v{o1[0], o1[1], o1[2], o1[3]},
                                    (f4v*)(outb + (size_t)(2 * l + 1) * HW));
    }

    // ---- direct levels 12..15: blend the landed quads ----
    #pragma unroll
    for (int k = 0; k < 4; ++k) {
        const int   l   = 12 + k;
        const float n   = (float)NSD[k];
        const float inv = 1.0f / n;
        const float rcp = 1.0f / inv;

        float o0[PPT], o1[PPT];
        #pragma unroll
        for (int p = 0; p < PPT; ++p) {
            const float cx = cxa[p], cy = cya[p];
            const float bx = floorf(cx * rcp);
            const float by = floorf(cy * rcp);

            const h8v h = __builtin_bit_cast(h8v, q[k][p]);

            const float wx_lo = ((bx + 1.0f) * inv - cx) * n;
            const float wx_hi = (cx - bx * inv) * n;
            const float wy_lo = ((by + 1.0f) * inv - cy) * n;
            const float wy_hi = (cy - by * inv) * n;

            const float r1x = (float)h[0] * wx_lo + (float)h[2] * wx_hi;
            const float r1y = (float)h[1] * wx_lo + (float)h[3] * wx_hi;
            const float r2x = (float)h[4] * wx_lo + (float)h[6] * wx_hi;
            const float r2y = (float)h[5] * wx_lo + (float)h[7] * wx_hi;
            o0[p] = (r1x * wy_lo + r2x * wy_hi) * INV_SCALE;
            o1[p] = (r1y * wy_lo + r2y * wy_hi) * INV_SCALE;
        }
        __builtin_nontemporal_store(f4v{o0[0], o0[1], o0[2], o0[3]},
                                    (f4v*)(outb + (size_t)(2 * l)     * HW));
        __builtin_nontemporal_store(f4v{o1[0], o1[1], o1[2], o1[3]},
                                    (f4v*)(outb + (size_t)(2 * l + 1) * HW));
    }
}

// ---- fallback (ws too small): R11 structure, proven 47.9us ----
__global__ __launch_bounds__(1024)
void hashenc_r11(const float* __restrict__ coord,
                 const float* __restrict__ table,
                 float* __restrict__ out)
{
    constexpr int NS[13]  = {8, 9, 11, 13, 16, 20, 24, 29, 35, 42, 50, 61, 73};
    constexpr int OFF[13] = {0, 100, 221, 390, 615, 939, 1423, 2099, 3060, 4429,
                             6365, 9069, 13038};
    constexpr int NSD[3]  = {88, 106, 127};

    extern __shared__ float2 smemd[];
    const float2* __restrict__ tab2 = reinterpret_cast<const float2*>(table);

    #pragma unroll
    for (int l = 0; l < 13; ++l) {
        const int W  = NS[l] + 2;
        const int SZ = W * W;
        const float2* __restrict__ tabl = tab2 + (size_t)l * TSIZE;
        for (int e = threadIdx.x; e < SZ; e += 1024) {
            const int j = e / W;
            const int i = e - j * W;
            smemd[OFF[l] + e] = tabl[((unsigned)i ^ ((unsigned)j * PRIME2)) & HMASK];
        }
    }

    const int g   = blockIdx.x * 1024 + threadIdx.x;
    const int P   = g << 1;
    const int b   = P >> 18;
    const int pos = P & (HW - 1);
    const float* cbase = coord + (size_t)b * (2 * HW);
    const float2 cxp = *reinterpret_cast<const float2*>(cbase + pos);
    const float2 cyp = *reinterpret_cast<const float2*>(cbase + HW + pos);
    const float cxa[2] = {cxp.x, cxp.y};
    const float cya[2] = {cyp.x, cyp.y};
    float* outb = out + (size_t)b * (32 * HW) + pos;

    __syncthreads();

    float2 gd[3][8];
    #pragma unroll
    for (int k = 0; k < 3; ++k) {
        const float n = (float)NSD[k];
        const float2* __restrict__ tabl = tab2 + (size_t)(13 + k) * TSIZE;
        #pragma unroll
        for (int p = 0; p < 2; ++p) {
            const int hx = (int)(cxa[p] * n);
            const int hy = (int)(cya[p] * n);
            const unsigned hyp0 = (unsigned)hy * PRIME2;
            const unsigned hyp1 = (unsigned)(hy + 1) * PRIME2;
            gd[k][p * 4 + 0] = tabl[((unsigned)hx       ^ hyp0) & HMASK];
            gd[k][p * 4 + 1] = tabl[((unsigned)(hx + 1) ^ hyp0) & HMASK];
            gd[k][p * 4 + 2] = tabl[((unsigned)hx       ^ hyp1) & HMASK];
            gd[k][p * 4 + 3] = tabl[((unsigned)(hx + 1) ^ hyp1) & HMASK];
        }
    }

    #pragma unroll
    for (int l = 0; l < 13; ++l) {
        const float n   = (float)NS[l];
        const float inv = 1.0f / n;
        const float rcp = 1.0f / inv;
        const int   W   = NS[l] + 2;
        const float2* __restrict__ sl = smemd + OFF[l];
        float o0[2], o1[2];
        #pragma unroll
        for (int p = 0; p < 2; ++p) {
            const float cx = cxa[p], cy = cya[p];
            const int hx = (int)(cx * n);
            const int hy = (int)(cy * n);
            const float bx = floorf(cx * rcp);
            const float by = floorf(cy * rcp);
            const int base = hy * W + hx;
            const float2 f00 = sl[base], f10 = sl[base + 1];
            const float2 f01 = sl[base + W], f11 = sl[base + W + 1];
            const float wx_lo = ((bx + 1.0f) * inv - cx) * n;
            const float wx_hi = (cx - bx * inv) * n;
            const float wy_lo = ((by + 1.0f) * inv - cy) * n;
            const float wy_hi = (cy - by * inv) * n;
            const float r1x = f00.x * wx_lo + f10.x * wx_hi;
            const float r1y = f00.y * wx_lo + f10.y * wx_hi;
            const float r2x = f01.x * wx_lo + f11.x * wx_hi;
            const float r2y = f01.y * wx_lo + f11.y * wx_hi;
            o0[p] = r1x * wy_lo + r2x * wy_hi;
            o1[p] = r1y * wy_lo + r2y * wy_hi;
        }
        *reinterpret_cast<float2*>(outb + (size_t)(2 * l)     * HW) = make_float2(o0[0], o0[1]);
        *reinterpret_cast<float2*>(outb + (size_t)(2 * l + 1) * HW) = make_float2(o1[0], o1[1]);
    }

    #pragma unroll
    for (int k = 0; k < 3; ++k) {
        const int   l   = 13 + k;
        const float n   = (float)NSD[k];
        const float inv = 1.0f / n;
        const float rcp = 1.0f / inv;
        float o0[2], o1[2];
        #pragma unroll
        for (int p = 0; p < 2; ++p) {
            const float cx = cxa[p], cy = cya[p];
            const float bx = floorf(cx * rcp);
            const float by = floorf(cy * rcp);
            const float2 f00 = gd[k][p * 4 + 0], f10 = gd[k][p * 4 + 1];
            const float2 f01 = gd[k][p * 4 + 2], f11 = gd[k][p * 4 + 3];
            const float wx_lo = ((bx + 1.0f) * inv - cx) * n;
            const float wx_hi = (cx - bx * inv) * n;
            const float wy_lo = ((by + 1.0f) * inv - cy) * n;
            const float wy_hi = (cy - by * inv) * n;
            const float r1x = f00.x * wx_lo + f10.x * wx_hi;
            const float r1y = f00.y * wx_lo + f10.y * wx_hi;
            const float r2x = f01.x * wx_lo + f11.x * wx_hi;
            const float r2y = f01.y * wx_lo + f11.y * wx_hi;
            o0[p] = r1x * wy_lo + r2x * wy_hi;
            o1[p] = r1y * wy_lo + r2y * wy_hi;
        }
        *reinterpret_cast<float2*>(outb + (size_t)(2 * l)     * HW) = make_float2(o0[0], o0[1]);
        *reinterpret_cast<float2*>(outb + (size_t)(2 * l + 1) * HW) = make_float2(o1[0], o1[1]);
    }
}

extern "C" void kernel_launch(void* const* d_in, const int* in_sizes, int n_in,
                              void* d_out, int out_size, void* d_ws, size_t ws_size,
                              hipStream_t stream) {
    const float* coord = (const float*)d_in[0];
    const float* table = (const float*)d_in[1];
    if (n_in >= 2 && in_sizes[0] > in_sizes[1]) {   // size-based disambiguation
        coord = (const float*)d_in[1];
        table = (const float*)d_in[0];
    }
    float* out = (float*)d_out;

    if (ws_size >= (size_t)WS_NEED && d_ws != nullptr) {
        unsigned* wsu = (unsigned*)d_ws;
        // phase 1: 13038 pair cells + 42030 quad cells = 55068 -> 216 blocks
        dehash_kernel<<<(ETOT + QTOT + 255) / 256, 256, 0, stream>>>(table, wsu);
        // phase 2: 1M px / (1024 thr * 4 px) = 256 blocks = 1/CU exactly (no tail)
        hashenc_fused<<<256, BLK, 0, stream>>>(coord, wsu, out);
    } else {
        const int lds_bytes = 18663 * (int)sizeof(float2);
        (void)hipFuncSetAttribute((const void*)hashenc_r11,
                                  hipFuncAttributeMaxDynamicSharedMemorySize,
                                  lds_bytes);
        hashenc_r11<<<512, 1024, lds_bytes, stream>>>(coord, table, out);
    }
}

// Round 23
// 40.708 us; speedup vs baseline: 1.1213x; 1.1213x over previous
//
#include <hip/hip_runtime.h>

#define HW 262144            // 512*512
#define TSIZE 524288         // 2^19 entries per level
#define HMASK 524287u
#define PRIME2 2654435761u

#define NLDS 11              // levels 0..10 staged in LDS (f16-packed entries)
#define ETOT 9069            // sum of (NS[l]+2)^2 for l<11 (entries)
#define EPAD 9072            // padded to uint4 multiple (36,288 B)
#define QTOT 45999           // 63^2+75^2+90^2+108^2+129^2 cells (levels 11..15)
#define QU4_OFF 2268         // EPAD u32 = 36,288 B -> /16 = 2268 uint4
#define WS_NEED (36288 + QTOT * 16)   // 772,272 B
#define BLK 512              // 1024 blocks = 4/CU exactly (36.3KB LDS), no tail
#define PPT 2                // pixels per thread (low VGPR -> more waves)
#define SCALE 1024.0f        // lift f16 values out of subnormal range (exact pow2)
#define INV_SCALE 0.0009765625f  // 2^-10, exact

typedef float    f2v __attribute__((ext_vector_type(2)));
typedef _Float16 h2v __attribute__((ext_vector_type(2)));
typedef _Float16 h8v __attribute__((ext_vector_type(8)));

__device__ __constant__ int c_W11[11]   = {10, 11, 13, 15, 18, 22, 26, 31, 37, 44, 52};
__device__ __constant__ int c_EOFF[12]  = {0, 100, 221, 390, 615, 939, 1423, 2099,
                                           3060, 4429, 6365, 9069};
__device__ __constant__ int c_WQ[5]     = {63, 75, 90, 108, 129};
__device__ __constant__ int c_QOFF[6]   = {0, 3969, 9594, 17694, 29358, 45999};

// Reference semantics (locked R1-R7): JAX/XLA f32:
//   hx = int32(fl32(cx*n)); bx = floorf(fl32(cx*rcp)), rcp = fl32(1/fl32(1/n));
//   NS[15] = 127.
// Ladder: R7 93 -> R11 47.9 -> R19 42.8 -> R21 41.0 (best) -> R22 45.6
// (pairing regression: bank-cycles fixed, 1-blk/CU barrier convoy).
// Cross-round fit: random loads cost 0.78us/M; structure-independent
// INTERCEPT ~37us with all pipes <30% busy => LATENCY-bound at 16 waves/CU.
// R23: occupancy attack with tail-free geometry: levels 0-10 in 36.3KB LDS,
// BLK=512 -> 1024 blocks = 4 blocks/CU = up to 32 waves/CU; levels 11-15
// via verified f16 quad cells; PPT=2 keeps VGPR low.

__device__ __forceinline__ unsigned pack_h2(float a, float b) {
    h2v h; h[0] = (_Float16)(a * SCALE); h[1] = (_Float16)(b * SCALE);
    return __builtin_bit_cast(unsigned, h);
}

// ---- phase 1: build dense scratch: f16 entries (lvls 0-10) + f16 quads (11-15) ----
__global__ __launch_bounds__(256)
void dehash_kernel(const float* __restrict__ table, unsigned* __restrict__ wsu)
{
    const int e = blockIdx.x * 256 + threadIdx.x;
    const float2* __restrict__ tab2 = reinterpret_cast<const float2*>(table);

    if (e < ETOT) {
        int l = 0;
        #pragma unroll
        for (int i = 1; i < NLDS; ++i) l += (e >= c_EOFF[i]);
        const int W   = c_W11[l];
        const int rel = e - c_EOFF[l];
        const int j   = rel / W;
        const int i2  = rel - j * W;
        const unsigned idx = ((unsigned)i2 ^ ((unsigned)j * PRIME2)) & HMASK;
        const float2 v = tab2[(size_t)l * TSIZE + idx];
        wsu[e] = pack_h2(v.x, v.y);
    } else if (e < ETOT + QTOT) {
        const int eq = e - ETOT;
        int k = 0;
        #pragma unroll
        for (int i = 1; i < 5; ++i) k += (eq >= c_QOFF[i]);
        const int W   = c_WQ[k];
        const int rel = eq - c_QOFF[k];
        const int j   = rel / W;
        const int i2  = rel - j * W;
        const float2* __restrict__ tabl = tab2 + (size_t)(11 + k) * TSIZE;
        const unsigned jp0 = (unsigned)j * PRIME2;
        const unsigned jp1 = (unsigned)(j + 1) * PRIME2;
        const float2 f00 = tabl[((unsigned)i2       ^ jp0) & HMASK];
        const float2 f10 = tabl[((unsigned)(i2 + 1) ^ jp0) & HMASK];
        const float2 f01 = tabl[((unsigned)i2       ^ jp1) & HMASK];
        const float2 f11 = tabl[((unsigned)(i2 + 1) ^ jp1) & HMASK];
        uint4 q;
        q.x = pack_h2(f00.x, f00.y);
        q.y = pack_h2(f10.x, f10.y);
        q.z = pack_h2(f01.x, f01.y);
        q.w = pack_h2(f11.x, f11.y);
        reinterpret_cast<uint4*>(wsu)[QU4_OFF + eq] = q;
    }
}

__device__ __forceinline__ float2 dec_h2(unsigned u) {
    const h2v h = __builtin_bit_cast(h2v, u);
    return make_float2((float)h[0], (float)h[1]);
}

// ---- phase 2: fused encode: 11 LDS levels + 5 quad-gather levels ----
__global__ __launch_bounds__(BLK)
void hashenc_fused(const float* __restrict__ coord,
                   const unsigned* __restrict__ wsu,
                   float* __restrict__ out)
{
    constexpr int NS[11]   = {8, 9, 11, 13, 16, 20, 24, 29, 35, 42, 50};
    constexpr int W11[11]  = {10, 11, 13, 15, 18, 22, 26, 31, 37, 44, 52};
    constexpr int EOFF[11] = {0, 100, 221, 390, 615, 939, 1423, 2099, 3060, 4429,
                              6365};
    constexpr int NSD[5]   = {61, 73, 88, 106, 127};
    constexpr int WQ[5]    = {63, 75, 90, 108, 129};
    constexpr int QOFF[5]  = {0, 3969, 9594, 17694, 29358};

    __shared__ __align__(16) unsigned smem[EPAD];   // 36,288 B -> 4 blocks/CU

    // ---- stage f16 entries from dense scratch (coalesced uint4) ----
    {
        const uint4* __restrict__ src = reinterpret_cast<const uint4*>(wsu);
        uint4* __restrict__ dst = reinterpret_cast<uint4*>(smem);
        for (int e = threadIdx.x; e < EPAD / 4; e += BLK)
            dst[e] = src[e];
    }

    const int g   = blockIdx.x * BLK + threadIdx.x;   // 0..524287
    const int P   = g << 1;                           // first of 2 pixels
    const int b   = P >> 18;                          // batch (HW = 2^18)
    const int pos = P & (HW - 1);

    const float* cbase = coord + (size_t)b * (2 * HW);
    const float2 cxp = *reinterpret_cast<const float2*>(cbase + pos);
    const float2 cyp = *reinterpret_cast<const float2*>(cbase + HW + pos);
    const float cxa[PPT] = {cxp.x, cxp.y};
    const float cya[PPT] = {cyp.x, cyp.y};

    float* outb = out + (size_t)b * (32 * HW) + pos;

    __syncthreads();

    // ---- issue all 10 direct quad loads NOW (latency hides under LDS work) ----
    uint4 q[5][PPT];
    {
        const uint4* __restrict__ quad = reinterpret_cast<const uint4*>(wsu) + QU4_OFF;
        #pragma unroll
        for (int k = 0; k < 5; ++k) {
            const float n = (float)NSD[k];
            #pragma unroll
            for (int p = 0; p < PPT; ++p) {
                const int hx = (int)(cxa[p] * n);
                const int hy = (int)(cya[p] * n);
                q[k][p] = quad[QOFF[k] + hy * WQ[k] + hx];
            }
        }
    }

    // ---- LDS levels 0..10 ----
    #pragma unroll
    for (int l = 0; l < NLDS; ++l) {
        const float n   = (float)NS[l];
        const float inv = 1.0f / n;
        const float rcp = 1.0f / inv;
        const int   W   = W11[l];
        const unsigned* __restrict__ sl = smem + EOFF[l];

        float o0[PPT], o1[PPT];
        #pragma unroll
        for (int p = 0; p < PPT; ++p) {
            const float cx = cxa[p], cy = cya[p];
            const int hx = (int)(cx * n);
            const int hy = (int)(cy * n);
            const float bx = floorf(cx * rcp);
            const float by = floorf(cy * rcp);

            const int base = hy * W + hx;
            const float2 f00 = dec_h2(sl[base]);
            const float2 f10 = dec_h2(sl[base + 1]);
            const float2 f01 = dec_h2(sl[base + W]);
            const float2 f11 = dec_h2(sl[base + W + 1]);

            const float wx_lo = ((bx + 1.0f) * inv - cx) * n;
            const float wx_hi = (cx - bx * inv) * n;
            const float wy_lo = ((by + 1.0f) * inv - cy) * n;
            const float wy_hi = (cy - by * inv) * n;

            const float r1x = f00.x * wx_lo + f10.x * wx_hi;
            const float r1y = f00.y * wx_lo + f10.y * wx_hi;
            const float r2x = f01.x * wx_lo + f11.x * wx_hi;
            const float r2y = f01.y * wx_lo + f11.y * wx_hi;
            o0[p] = (r1x * wy_lo + r2x * wy_hi) * INV_SCALE;
            o1[p] = (r1y * wy_lo + r2y * wy_hi) * INV_SCALE;
        }
        __builtin_nontemporal_store(f2v{o0[0], o0[1]},
                                    (f2v*)(outb + (size_t)(2 * l)     * HW));
        __builtin_nontemporal_store(f2v{o1[0], o1[1]},
                                    (f2v*)(outb + (size_t)(2 * l + 1) * HW));
    }

    // ---- direct levels 11..15: blend the landed quads ----
    #pragma unroll
    for (int k = 0; k < 5; ++k) {
        const int   l   = 11 + k;
        const float n   = (float)NSD[k];
        const float inv = 1.0f / n;
        const float rcp = 1.0f / inv;

        float o0[PPT], o1[PPT];
        #pragma unroll
        for (int p = 0; p < PPT; ++p) {
            const float cx = cxa[p], cy = cya[p];
            const float bx = floorf(cx * rcp);
            const float by = floorf(cy * rcp);

            const h8v h = __builtin_bit_cast(h8v, q[k][p]);

            const float wx_lo = ((bx + 1.0f) * inv - cx) * n;
            const float wx_hi = (cx - bx * inv) * n;
            const float wy_lo = ((by + 1.0f) * inv - cy) * n;
            const float wy_hi = (cy - by * inv) * n;

            const float r1x = (float)h[0] * wx_lo + (float)h[2] * wx_hi;
            const float r1y = (float)h[1] * wx_lo + (float)h[3] * wx_hi;
            const float r2x = (float)h[4] * wx_lo + (float)h[6] * wx_hi;
            const float r2y = (float)h[5] * wx_lo + (float)h[7] * wx_hi;
            o0[p] = (r1x * wy_lo + r2x * wy_hi) * INV_SCALE;
            o1[p] = (r1y * wy_lo + r2y * wy_hi) * INV_SCALE;
        }
        __builtin_nontemporal_store(f2v{o0[0], o0[1]},
                                    (f2v*)(outb + (size_t)(2 * l)     * HW));
        __builtin_nontemporal_store(f2v{o1[0], o1[1]},
                                    (f2v*)(outb + (size_t)(2 * l + 1) * HW));
    }
}

// ---- fallback (ws too small): R11 structure, proven 47.9us ----
__global__ __launch_bounds__(1024)
void hashenc_r11(const float* __restrict__ coord,
                 const float* __restrict__ table,
                 float* __restrict__ out)
{
    constexpr int NS[13]  = {8, 9, 11, 13, 16, 20, 24, 29, 35, 42, 50, 61, 73};
    constexpr int OFF[13] = {0, 100, 221, 390, 615, 939, 1423, 2099, 3060, 4429,
                             6365, 9069, 13038};
    constexpr int NSD[3]  = {88, 106, 127};

    extern __shared__ float2 smemd[];
    const float2* __restrict__ tab2 = reinterpret_cast<const float2*>(table);

    #pragma unroll
    for (int l = 0; l < 13; ++l) {
        const int W  = NS[l] + 2;
        const int SZ = W * W;
        const float2* __restrict__ tabl = tab2 + (size_t)l * TSIZE;
        for (int e = threadIdx.x; e < SZ; e += 1024) {
            const int j = e / W;
            const int i = e - j * W;
            smemd[OFF[l] + e] = tabl[((unsigned)i ^ ((unsigned)j * PRIME2)) & HMASK];
        }
    }

    const int g   = blockIdx.x * 1024 + threadIdx.x;
    const int P   = g << 1;
    const int b   = P >> 18;
    const int pos = P & (HW - 1);
    const float* cbase = coord + (size_t)b * (2 * HW);
    const float2 cxp = *reinterpret_cast<const float2*>(cbase + pos);
    const float2 cyp = *reinterpret_cast<const float2*>(cbase + HW + pos);
    const float cxa[2] = {cxp.x, cxp.y};
    const float cya[2] = {cyp.x, cyp.y};
    float* outb = out + (size_t)b * (32 * HW) + pos;

    __syncthreads();

    float2 gd[3][8];
    #pragma unroll
    for (int k = 0; k < 3; ++k) {
        const float n = (float)NSD[k];
        const float2* __restrict__ tabl = tab2 + (size_t)(13 + k) * TSIZE;
        #pragma unroll
        for (int p = 0; p < 2; ++p) {
            const int hx = (int)(cxa[p] * n);
            const int hy = (int)(cya[p] * n);
            const unsigned hyp0 = (unsigned)hy * PRIME2;
            const unsigned hyp1 = (unsigned)(hy + 1) * PRIME2;
            gd[k][p * 4 + 0] = tabl[((unsigned)hx       ^ hyp0) & HMASK];
            gd[k][p * 4 + 1] = tabl[((unsigned)(hx + 1) ^ hyp0) & HMASK];
            gd[k][p * 4 + 2] = tabl[((unsigned)hx       ^ hyp1) & HMASK];
            gd[k][p * 4 + 3] = tabl[((unsigned)(hx + 1) ^ hyp1) & HMASK];
        }
    }

    #pragma unroll
    for (int l = 0; l < 13; ++l) {
        const float n   = (float)NS[l];
        const float inv = 1.0f / n;
        const float rcp = 1.0f / inv;
        const int   W   = NS[l] + 2;
        const float2* __restrict__ sl = smemd + OFF[l];
        float o0[2], o1[2];
        #pragma unroll
        for (int p = 0; p < 2; ++p) {
            const float cx = cxa[p], cy = cya[p];
            const int hx = (int)(cx * n);
            const int hy = (int)(cy * n);
            const float bx = floorf(cx * rcp);
            const float by = floorf(cy * rcp);
            const int base = hy * W + hx;
            const float2 f00 = sl[base], f10 = sl[base + 1];
            const float2 f01 = sl[base + W], f11 = sl[base + W + 1];
            const float wx_lo = ((bx + 1.0f) * inv - cx) * n;
            const float wx_hi = (cx - bx * inv) * n;
            const float wy_lo = ((by + 1.0f) * inv - cy) * n;
            const float wy_hi = (cy - by * inv) * n;
            const float r1x = f00.x * wx_lo + f10.x * wx_hi;
            const float r1y = f00.y * wx_lo + f10.y * wx_hi;
            const float r2x = f01.x * wx_lo + f11.x * wx_hi;
            const float r2y = f01.y * wx_lo + f11.y * wx_hi;
            o0[p] = r1x * wy_lo + r2x * wy_hi;
            o1[p] = r1y * wy_lo + r2y * wy_hi;
        }
        *reinterpret_cast<float2*>(outb + (size_t)(2 * l)     * HW) = make_float2(o0[0], o0[1]);
        *reinterpret_cast<float2*>(outb + (size_t)(2 * l + 1) * HW) = make_float2(o1[0], o1[1]);
    }

    #pragma unroll
    for (int k = 0; k < 3; ++k) {
        const int   l   = 13 + k;
        const float n   = (float)NSD[k];
        const float inv = 1.0f / n;
        const float rcp = 1.0f / inv;
        float o0[2], o1[2];
        #pragma unroll
        for (int p = 0; p < 2; ++p) {
            const float cx = cxa[p], cy = cya[p];
            const float bx = floorf(cx * rcp);
            const float by = floorf(cy * rcp);
            const float2 f00 = gd[k][p * 4 + 0], f10 = gd[k][p * 4 + 1];
            const float2 f01 = gd[k][p * 4 + 2], f11 = gd[k][p * 4 + 3];
            const float wx_lo = ((bx + 1.0f) * inv - cx) * n;
            const float wx_hi = (cx - bx * inv) * n;
            const float wy_lo = ((by + 1.0f) * inv - cy) * n;
            const float wy_hi = (cy - by * inv) * n;
            const float r1x = f00.x * wx_lo + f10.x * wx_hi;
            const float r1y = f00.y * wx_lo + f10.y * wx_hi;
            const float r2x = f01.x * wx_lo + f11.x * wx_hi;
            const float r2y = f01.y * wx_lo + f11.y * wx_hi;
            o0[p] = r1x * wy_lo + r2x * wy_hi;
            o1[p] = r1y * wy_lo + r2y * wy_hi;
        }
        *reinterpret_cast<float2*>(outb + (size_t)(2 * l)     * HW) = make_float2(o0[0], o0[1]);
        *reinterpret_cast<float2*>(outb + (size_t)(2 * l + 1) * HW) = make_float2(o1[0], o1[1]);
    }
}

extern "C" void kernel_launch(void* const* d_in, const int* in_sizes, int n_in,
                              void* d_out, int out_size, void* d_ws, size_t ws_size,
                              hipStream_t stream) {
    const float* coord = (const float*)d_in[0];
    const float* table = (const float*)d_in[1];
    if (n_in >= 2 && in_sizes[0] > in_sizes[1]) {   // size-based disambiguation
        coord = (const float*)d_in[1];
        table = (const float*)d_in[0];
    }
    float* out = (float*)d_out;

    if (ws_size >= (size_t)WS_NEED && d_ws != nullptr) {
        unsigned* wsu = (unsigned*)d_ws;
        // phase 1: 9069 entries + 45999 quad cells = 55068 -> 216 blocks
        dehash_kernel<<<(ETOT + QTOT + 255) / 256, 256, 0, stream>>>(table, wsu);
        // phase 2: 1M px / (512 thr * 2 px) = 1024 blocks = 4/CU exactly (no tail)
        hashenc_fused<<<1024, BLK, 0, stream>>>(coord, wsu, out);
    } else {
        const int lds_bytes = 18663 * (int)sizeof(float2);
        (void)hipFuncSetAttribute((const void*)hashenc_r11,
                                  hipFuncAttributeMaxDynamicSharedMemorySize,
                                  lds_bytes);
        hashenc_r11<<<512, 1024, lds_bytes, stream>>>(coord, table, out);
    }
}